// Round 1
// 108.307 us; speedup vs baseline: 1.0457x; 1.0457x over previous
//
#include <hip/hip_runtime.h>
#include <math.h>

#define BB 8
#define CC 64
#define NN 4096
#define CI 8
#define GAMMA 0.1f
// exp(s/sqrt(8)) = exp2(s * log2(e)/sqrt(8)); folded into k in qkv.
#define SCALE (1.44269504088896f * 0.35355339059327f)
#define NSPLIT 8

typedef float v4f  __attribute__((ext_vector_type(4)));
typedef float v16f __attribute__((ext_vector_type(16)));
typedef __bf16 bf16x8 __attribute__((ext_vector_type(8)));
typedef __bf16 bf16x4 __attribute__((ext_vector_type(4)));
typedef unsigned int u32x2 __attribute__((ext_vector_type(2)));

__device__ __forceinline__ float fast_exp2(float x) {
    return __builtin_amdgcn_exp2f(x);
}

// Pack two f32 into one u32 of 2 bf16 (T12 recipe; no builtin on gfx950).
__device__ __forceinline__ unsigned int cvt_pk_bf16(float lo, float hi) {
    unsigned int r;
    asm("v_cvt_pk_bf16_f32 %0, %1, %2" : "=v"(r) : "v"(lo), "v"(hi));
    return r;
}

// R7-proven qkv. Grid (NN/32, BB); block 256 = 8 i-groups x 32 n.
// qbh[b][n][8], kbh[b][m][8] (k*SCALE), vbh[b][i][N] bf16; zeros attab[b][9][N].
__global__ __launch_bounds__(256) void qkv_kernel(
        const float* __restrict__ x,
        const float* __restrict__ Wq, const float* __restrict__ Wk,
        const float* __restrict__ Wv,
        __bf16* __restrict__ qbh, __bf16* __restrict__ kbh,
        __bf16* __restrict__ vbh, float* __restrict__ attab) {
    __shared__ float sw[3 * CI * CC];     // 6 KB: Wq | Wk*SCALE | Wv
    __shared__ unsigned short sq[32 * 8]; // bf16 tile [n_local][i]
    __shared__ unsigned short sk[32 * 8];
    const int t = threadIdx.x;
    const int i  = t >> 5;
    const int nl = t & 31;
    const int b  = blockIdx.y;
    const int n0 = blockIdx.x * 32;

    for (int idx = t; idx < CI * CC; idx += 256) {
        sw[idx]                = Wq[idx];
        sw[CI * CC + idx]      = Wk[idx] * SCALE;
        sw[2 * CI * CC + idx]  = Wv[idx];
    }
    int lin = (blockIdx.y * (NN / 32) + blockIdx.x) * 256 + t;
    for (int idx = lin; idx < BB * 9 * NN; idx += BB * NN * CI) attab[idx] = 0.f;
    __syncthreads();

    const int n = n0 + nl;
    const float* xp = x + ((size_t)b * CC) * NN + n;
    const v4f* wq4 = (const v4f*)(sw + i * CC);
    const v4f* wk4 = (const v4f*)(sw + CI * CC + i * CC);
    const v4f* wv4 = (const v4f*)(sw + 2 * CI * CC + i * CC);
    float qa = 0.f, ka = 0.f, va = 0.f;
#pragma unroll 4
    for (int c4 = 0; c4 < CC / 4; ++c4) {
        v4f wq = wq4[c4], wk = wk4[c4], wv = wv4[c4];   // LDS broadcast b128
        float x0 = xp[(size_t)(c4 * 4 + 0) * NN];
        float x1 = xp[(size_t)(c4 * 4 + 1) * NN];
        float x2 = xp[(size_t)(c4 * 4 + 2) * NN];
        float x3 = xp[(size_t)(c4 * 4 + 3) * NN];
        qa = fmaf(wq.x, x0, qa); ka = fmaf(wk.x, x0, ka); va = fmaf(wv.x, x0, va);
        qa = fmaf(wq.y, x1, qa); ka = fmaf(wk.y, x1, ka); va = fmaf(wv.y, x1, va);
        qa = fmaf(wq.z, x2, qa); ka = fmaf(wk.z, x2, ka); va = fmaf(wv.z, x2, va);
        qa = fmaf(wq.w, x3, qa); ka = fmaf(wk.w, x3, ka); va = fmaf(wv.w, x3, va);
    }
    __bf16 vb = (__bf16)va;
    vbh[((size_t)b * CI + i) * NN + n] = vb;
    __bf16 qb = (__bf16)qa, kb2 = (__bf16)ka;
    sq[nl * 8 + i] = *(unsigned short*)&qb;
    sk[nl * 8 + i] = *(unsigned short*)&kb2;
    __syncthreads();
    if (t < 32) {
        *(uint4*)(qbh + ((size_t)b * NN + n0 + t) * 8) = *(const uint4*)(sq + t * 8);
        *(uint4*)(kbh + ((size_t)b * NN + n0 + t) * 8) = *(const uint4*)(sk + t * 8);
    }
}

// 32x32-tile MFMA attention, LDS-FREE transpose (T12: cvt_pk + permlane32_swap).
// Previous version round-tripped E through LDS per chunk (4 ds_write_b64 +
// 2 ds_read_b128 + two ~120cy LDS latencies in the SAME wave's dependency
// chain) purely to transpose S's C-layout into a 16x16x32 B-layout. Key
// observation: the 32x32x16 B-layout B[k=hi*8+j][col=ln] keeps col=lane&31 —
// identical to S's C-layout col. Lane (hi,ln) already holds E for
// n in {4h+q, 8+4h+q, 16+4h+q, 24+4h+q} (q=0..3); its partner lane (hi^1,ln)
// holds the complementary quads. So the transpose is exactly 4 lane-half
// swaps: pack pairs with v_cvt_pk_bf16_f32, then v_permlane32_swap_b32:
//   swap(pk0,pk2) -> words {w0,w2} of the k=0..15 B-frag (both halves)
//   swap(pk1,pk3) -> {w1,w3};  swap(pk4,pk6)/swap(pk5,pk7) -> k=16..31 frag.
// PV = two 32x32x16 into ONE v16f acc; A-frag rows = i (0..7 = V rows,
// row 8 = ones for the denominator), C rows 0..8 live.
// S C-layout (HW-verified): col=lane&31, row=(reg&3)+8*(reg>>2)+4*(lane>>5).
// |scores| < ~2 -> exp without max-subtraction safe. NSPLIT=8 -> 8192 waves.
// Grid (NN/128, NSPLIT, BB) = 2048 blocks x 4 waves; wave = 32-m tile.
__global__ __launch_bounds__(256) void att_kernel(
        const __bf16* __restrict__ qbh, const __bf16* __restrict__ kbh,
        const __bf16* __restrict__ vbh, float* __restrict__ attab) {
    const int t = threadIdx.x;
    const int w    = t >> 6;
    const int l    = t & 63;
    const int ln   = l & 31;        // S: A-row (n) / B-col (m); C col (m)
    const int hi   = l >> 5;        // k-half selector (k = hi*8 + j)
    const int b  = blockIdx.z;
    const int m0 = blockIdx.x * 128 + w * 32;
    const int nbase = blockIdx.y * (NN / NSPLIT);   // 512 per wave
    const int NCH = (NN / NSPLIT) / 32;             // 16 chunks of 32 n

    bf16x8 zero8, ones8;
#pragma unroll
    for (int z = 0; z < 8; ++z) { zero8[z] = (__bf16)0.0f; ones8[z] = (__bf16)1.0f; }

    // S B-frag (loop-invariant): B[k=hi*8+j][col=ln] = K[m0+ln][j], hi==0 live
    bf16x8 kfragB = hi ? zero8
                       : *(const bf16x8*)(kbh + ((size_t)b * NN + m0 + ln) * 8);

    const __bf16* qrow = qbh + (size_t)b * NN * 8;
    // PV A-frag: A[row=ln][k=hi*8+j] = V[i=ln][n]; rows 8..31 ones/zero.
    const __bf16* vrow = vbh + ((size_t)b * CI + (ln & 7)) * NN;
    const bool v_live = (ln < 8);
    const bool v_ones = (ln == 8);

    v16f acc = {0.f,0.f,0.f,0.f,0.f,0.f,0.f,0.f,0.f,0.f,0.f,0.f,0.f,0.f,0.f,0.f};

    for (int ch = 0; ch < NCH; ++ch) {
        const int nc = nbase + ch * 32;
        // S A-frag: A[row=ln][k=hi*8+j] = Q[nc+ln][j], hi==0 live
        bf16x8 qfrag = hi ? zero8
                          : *(const bf16x8*)(qrow + (size_t)(nc + ln) * 8);
        // PV A-frags for the two k-halves (n = nc+hi*8+j and nc+16+hi*8+j)
        bf16x8 va0 = v_live ? *(const bf16x8*)(vrow + nc + hi * 8)
                            : (v_ones ? ones8 : zero8);
        bf16x8 va1 = v_live ? *(const bf16x8*)(vrow + nc + 16 + hi * 8)
                            : (v_ones ? ones8 : zero8);

        v16f S = __builtin_amdgcn_mfma_f32_32x32x16_bf16(
            qfrag, kfragB,
            (v16f){0.f,0.f,0.f,0.f,0.f,0.f,0.f,0.f,0.f,0.f,0.f,0.f,0.f,0.f,0.f,0.f},
            0, 0, 0);

        // exp + pack: pk[g] = bf16 pair of S regs (2g, 2g+1)
        //   pk0=n(4h,4h+1) pk1=n(4h+2,4h+3) pk2=n(8+4h,..) pk3=n(10+4h,..)
        //   pk4=n(16+4h,..) pk5=n(18+4h,..) pk6=n(24+4h,..) pk7=n(26+4h,..)
        unsigned int pk0 = cvt_pk_bf16(fast_exp2(S[0]),  fast_exp2(S[1]));
        unsigned int pk1 = cvt_pk_bf16(fast_exp2(S[2]),  fast_exp2(S[3]));
        unsigned int pk2 = cvt_pk_bf16(fast_exp2(S[4]),  fast_exp2(S[5]));
        unsigned int pk3 = cvt_pk_bf16(fast_exp2(S[6]),  fast_exp2(S[7]));
        unsigned int pk4 = cvt_pk_bf16(fast_exp2(S[8]),  fast_exp2(S[9]));
        unsigned int pk5 = cvt_pk_bf16(fast_exp2(S[10]), fast_exp2(S[11]));
        unsigned int pk6 = cvt_pk_bf16(fast_exp2(S[12]), fast_exp2(S[13]));
        unsigned int pk7 = cvt_pk_bf16(fast_exp2(S[14]), fast_exp2(S[15]));

        // Lane-half exchange -> PV B-frags B[k=hi*8+j][col=ln] = E[n][m]
        u32x2 r02 = __builtin_amdgcn_permlane32_swap(pk0, pk2, false, false);
        u32x2 r13 = __builtin_amdgcn_permlane32_swap(pk1, pk3, false, false);
        u32x2 r46 = __builtin_amdgcn_permlane32_swap(pk4, pk6, false, false);
        u32x2 r57 = __builtin_amdgcn_permlane32_swap(pk5, pk7, false, false);

        union { unsigned int u[4]; bf16x8 f; } e0f, e1f;
        e0f.u[0] = r02[0]; e0f.u[1] = r13[0]; e0f.u[2] = r02[1]; e0f.u[3] = r13[1];
        e1f.u[0] = r46[0]; e1f.u[1] = r57[0]; e1f.u[2] = r46[1]; e1f.u[3] = r57[1];

        acc = __builtin_amdgcn_mfma_f32_32x32x16_bf16(va0, e0f.f, acc, 0, 0, 0);
        acc = __builtin_amdgcn_mfma_f32_32x32x16_bf16(va1, e1f.f, acc, 0, 0, 0);
    }

    // Epilogue: C row io=(r&3)+8*(r>>2)+4*hi, col m0+ln; rows 0..7 = sum e*v_i,
    // row 8 = sum e. Rows >8 are zero by construction -> skip.
    float* ap = attab + (size_t)b * 9 * NN + m0 + ln;
#pragma unroll
    for (int r = 0; r < 16; ++r) {
        int io = (r & 3) + 8 * (r >> 2) + 4 * hi;
        if (io < 9) atomicAdd(ap + (size_t)io * NN, acc[r]);
    }
}

// R7-proven out. Grid (NN/1024, CC, BB); block 256; float4 per thread.
__global__ __launch_bounds__(256) void out_kernel(
        const float* __restrict__ x, const float* __restrict__ Wout,
        const float* __restrict__ attab, float* __restrict__ out) {
    const int t = threadIdx.x;
    const int c = blockIdx.y;
    const int b = blockIdx.z;
    const int m = (blockIdx.x * 256 + t) * 4;
    const float* ap = attab + (size_t)b * 9 * NN + m;
    v4f sum = *(const v4f*)(ap + (size_t)8 * NN);
    v4f s = {0.f, 0.f, 0.f, 0.f};
#pragma unroll
    for (int i = 0; i < CI; ++i) {
        float wgt = Wout[c * CI + i];               // uniform -> s_load
        v4f a = *(const v4f*)(ap + (size_t)i * NN);
        s.x = fmaf(wgt, a.x, s.x);
        s.y = fmaf(wgt, a.y, s.y);
        s.z = fmaf(wgt, a.z, s.z);
        s.w = fmaf(wgt, a.w, s.w);
    }
    size_t o = ((size_t)b * CC + c) * NN + m;
    v4f xv = *(const v4f*)(x + o);
    v4f r;
    r.x = xv.x + GAMMA * (s.x / sum.x);
    r.y = xv.y + GAMMA * (s.y / sum.y);
    r.z = xv.z + GAMMA * (s.z / sum.z);
    r.w = xv.w + GAMMA * (s.w / sum.w);
    *(v4f*)(out + o) = r;
}

extern "C" void kernel_launch(void* const* d_in, const int* in_sizes, int n_in,
                              void* d_out, int out_size, void* d_ws, size_t ws_size,
                              hipStream_t stream) {
    const float* x    = (const float*)d_in[0];
    const float* Wq   = (const float*)d_in[1];
    const float* Wk   = (const float*)d_in[2];
    const float* Wv   = (const float*)d_in[3];
    const float* Wout = (const float*)d_in[4];
    float* out = (float*)d_out;

    // ws: qbh [B][N][8] bf16 | kbh [B][N][8] bf16 | vbh [B][8][N] bf16 |
    //     attab [B][9][N] fp32
    __bf16* qbh = (__bf16*)d_ws;
    __bf16* kbh = qbh + (size_t)BB * NN * 8;
    __bf16* vbh = kbh + (size_t)BB * NN * 8;
    float* attab = (float*)(vbh + (size_t)BB * NN * 8);

    qkv_kernel<<<dim3(NN / 32, BB), 256, 0, stream>>>(x, Wq, Wk, Wv, qbh, kbh, vbh, attab);
    att_kernel<<<dim3(NN / 128, NSPLIT, BB), 256, 0, stream>>>(qbh, kbh, vbh, attab);
    out_kernel<<<dim3(NN / 1024, CC, BB), 256, 0, stream>>>(x, Wout, attab, out);
}